// Round 10
// baseline (289.730 us; speedup 1.0000x reference)
//
#include <hip/hip_runtime.h>

// ---------------------------------------------------------------------------
// CrossAttentionBlockPatched: B=4, Lq=512, Lkv=2048, DIM=1024, H=16, hd=64,
// MLP_HIDDEN=4096, TAU=2.0, EPS=1e-6. fp32 in/out.
// Big GEMMs (kv-proj, fc1, fc2): MX-scaled fp8 e4m3 MFMA (K=128, unit
// scales; weights pre-scaled x16). Small GEMMs (q-proj, Wo) + attention:
// bf16 MFMA. fp32 accumulation.
// r6..r14: see history. r15: all fp8 GEMMs ported to
// mfma_scale_f32_16x16x128_f8f6f4 (2.1x MFMA rate; C/D layout identical to
// 16x16x32 family so epilogues unchanged). BK=128, 32 B fragments via two
// swizzled ds_read_b128. qkv pool 64 KB (2 blk/CU), fc 48 KB (3 blk/CU).
// ---------------------------------------------------------------------------

typedef __attribute__((ext_vector_type(8))) short short8_t;   // 8 x bf16
typedef __attribute__((ext_vector_type(4))) short short4_t;   // 4 x bf16
typedef __attribute__((ext_vector_type(4))) float f32x4_t;    // 4 x fp32
typedef __attribute__((ext_vector_type(8))) int int8v_t;      // 32 x fp8
typedef __attribute__((ext_vector_type(4))) int int4v_t;      // 16 B

#define WSCALE 16.0f
#define OSC (1.0f / 16.0f)
#define SCL1 127   // e8m0 exponent 127 -> scale 1.0

__device__ __forceinline__ float b2f(short s) {
    union { float f; unsigned u; } c;
    c.u = ((unsigned)(unsigned short)s) << 16;
    return c.f;
}
__device__ __forceinline__ short f2b(float f) {
    union { float f; unsigned u; } c;
    c.f = f;
    unsigned u = c.u;
    unsigned r = (u + 0x7FFFu + ((u >> 16) & 1u)) >> 16;
    return (short)r;
}
__device__ __forceinline__ unsigned cvt_pk_bf16(float lo, float hi) {
    unsigned r;
    asm("v_cvt_pk_bf16_f32 %0, %1, %2" : "=v"(r) : "v"(lo), "v"(hi));
    return r;
}
__device__ __forceinline__ unsigned f2f8_pk4(float a, float b, float c, float d) {
    int lo = __builtin_amdgcn_cvt_pk_fp8_f32(a, b, 0, false);
    return (unsigned)__builtin_amdgcn_cvt_pk_fp8_f32(c, d, lo, true);
}
__device__ __forceinline__ unsigned char f2f8(float a) {
    return (unsigned char)(__builtin_amdgcn_cvt_pk_fp8_f32(a, a, 0, false) & 0xff);
}

// async global -> LDS, 16 B per lane; lds base must be wave-uniform.
__device__ __forceinline__ void gload16(const void* g, void* l) {
    __builtin_amdgcn_global_load_lds(
        (const __attribute__((address_space(1))) void*)g,
        (__attribute__((address_space(3))) void*)l, 16, 0, 0);
}

// 32 B fp8 fragment from two swizzled 16 B LDS groups.
__device__ __forceinline__ int8v_t ld32(const unsigned char* base, int g0, int g1) {
    const int4v_t lo = *(const int4v_t*)(base + g0);
    const int4v_t hi = *(const int4v_t*)(base + g1);
    int8v_t r;
    r[0] = lo[0]; r[1] = lo[1]; r[2] = lo[2]; r[3] = lo[3];
    r[4] = hi[0]; r[5] = hi[1]; r[6] = hi[2]; r[7] = hi[3];
    return r;
}

// ---------------------------------------------------------------------------
// LayerNorm row helper: fp32 in; OUT8=0 -> bf16 out, OUT8=1 -> fp8 out.
// ---------------------------------------------------------------------------
template <int OUT8>
__device__ __forceinline__ void ln_row(
    const float* __restrict__ x, const float* __restrict__ w,
    const float* __restrict__ bia, void* __restrict__ y,
    int row, int tid, float* red)
{
    const float4 t = *(const float4*)(x + (size_t)row * 1024 + tid * 4);
    float v[4] = {t.x, t.y, t.z, t.w};
    float s = v[0] + v[1] + v[2] + v[3];
    float s2 = v[0]*v[0] + v[1]*v[1] + v[2]*v[2] + v[3]*v[3];
    #pragma unroll
    for (int off = 1; off < 64; off <<= 1) {
        s  += __shfl_xor(s, off);
        s2 += __shfl_xor(s2, off);
    }
    const int wave = tid >> 6, lane = tid & 63;
    if (lane == 0) { red[wave] = s; red[4 + wave] = s2; }
    __syncthreads();
    s  = red[0] + red[1] + red[2] + red[3];
    s2 = red[4] + red[5] + red[6] + red[7];
    const float mu  = s * (1.0f / 1024.0f);
    const float var = s2 * (1.0f / 1024.0f) - mu * mu;
    const float rstd = rsqrtf(var + 1e-6f);
    const float4 wv = *(const float4*)(w + tid * 4);
    const float4 bv = *(const float4*)(bia + tid * 4);
    const float o0 = (v[0] - mu) * rstd * wv.x + bv.x;
    const float o1 = (v[1] - mu) * rstd * wv.y + bv.y;
    const float o2 = (v[2] - mu) * rstd * wv.z + bv.z;
    const float o3 = (v[3] - mu) * rstd * wv.w + bv.w;
    if (OUT8) {
        ((unsigned*)y)[(size_t)row * 256 + tid] = f2f8_pk4(o0, o1, o2, o3);
    } else {
        short4 o;
        o.x = f2b(o0); o.y = f2b(o1); o.z = f2b(o2); o.w = f2b(o3);
        *(short4*)((short*)y + (size_t)row * 1024 + tid * 4) = o;
    }
}

// ---------------------------------------------------------------------------
// prep: q-LN -> bf16 (blocks 0..2047), kv-LN -> fp8 (2048..10239), weight
// casts (10240..22527): Wq,Wo -> bf16; Wkv,fc1,fc2 -> fp8 scaled x16.
// ---------------------------------------------------------------------------
__global__ __launch_bounds__(256) void prep_kernel(
    const float* __restrict__ qt, const float* __restrict__ kvt,
    const float* __restrict__ qlw, const float* __restrict__ qlb,
    const float* __restrict__ klw, const float* __restrict__ klb,
    short* __restrict__ qn, unsigned char* __restrict__ kvn8,
    const float* __restrict__ Wq, const float* __restrict__ Wo,
    const float* __restrict__ Wk, const float* __restrict__ Wv,
    const float* __restrict__ fc1w, const float* __restrict__ fc2w,
    short* __restrict__ Wq_b, short* __restrict__ Wo_b,
    unsigned char* __restrict__ Wkv8,
    unsigned char* __restrict__ fc1_8, unsigned char* __restrict__ fc2_8)
{
    __shared__ float red[8];
    const int bid = blockIdx.x, tid = threadIdx.x;
    if (bid < 2048) {
        ln_row<0>(qt, qlw, qlb, qn, bid, tid, red);
    } else if (bid < 10240) {
        ln_row<1>(kvt, klw, klb, kvn8, bid - 2048, tid, red);
    } else {
        int f = (bid - 10240) * 256 + tid;   // float4 index, total 3145728
        if (f < 524288) {                    // Wq, Wo -> bf16
            const float* src = (f < 262144) ? Wq : Wo;
            short* dst = (f < 262144) ? Wq_b : Wo_b;
            const int off = f & 262143;
            const float4 v = ((const float4*)src)[off];
            short4 o;
            o.x = f2b(v.x); o.y = f2b(v.y); o.z = f2b(v.z); o.w = f2b(v.w);
            ((short4*)dst)[off] = o;
        } else {                             // fp8 x16
            const float* src; unsigned* dst; int off;
            if (f < 1048576) {
                off = f - 524288;
                src = (off < 262144) ? Wk : Wv;
                dst = (unsigned*)Wkv8;
                if (off >= 262144) { src = Wv; }
                const int so = (off < 262144) ? off : off - 262144;
                const float4 v = ((const float4*)src)[so];
                dst[off] = f2f8_pk4(v.x * WSCALE, v.y * WSCALE,
                                    v.z * WSCALE, v.w * WSCALE);
                return;
            } else if (f < 2097152) {
                off = f - 1048576; src = fc1w; dst = (unsigned*)fc1_8;
            } else {
                off = f - 2097152; src = fc2w; dst = (unsigned*)fc2_8;
            }
            const float4 v = ((const float4*)src)[off];
            dst[off] = f2f8_pk4(v.x * WSCALE, v.y * WSCALE,
                                v.z * WSCALE, v.w * WSCALE);
        }
    }
}

// ---------------------------------------------------------------------------
// Standalone LN for MLP: fp32 in, fp8 out.
// ---------------------------------------------------------------------------
__global__ __launch_bounds__(256) void ln8_kernel(
    const float* __restrict__ x, const float* __restrict__ w,
    const float* __restrict__ bia, unsigned char* __restrict__ y)
{
    __shared__ float red[8];
    ln_row<1>(x, w, bia, y, blockIdx.x, threadIdx.x, red);
}

// ---------------------------------------------------------------------------
// bf16 GEMM (Wo): BN=128, BK=64, dbuf single-barrier K-loop,
// 128 B LDS rows + 3-bit XOR swizzle. Wave tile (BM/2)x64.
// EPI: 1 outF = resF + alpha*(acc+bias); 4 l2norm(64-col head) bf16 out.
// ---------------------------------------------------------------------------
template <int EPI, int BM>
__global__ __launch_bounds__(256) void gemm_bt_kernel(
    const short* __restrict__ A, const short* __restrict__ W,
    int M, int N, int Ks, int Kst,
    const float* __restrict__ bias,
    const float* __restrict__ resF,
    const float* __restrict__ alpha,
    short* __restrict__ out16,
    float* __restrict__ outF)
{
    constexpr int MI = (BM + 31) / 32;
    __shared__ __attribute__((aligned(16))) short As[2][BM * 64];
    __shared__ __attribute__((aligned(16))) short Bs[2][128 * 64];
    const int bm = blockIdx.y * BM, bn = blockIdx.x * 128;
    const int tid = threadIdx.x;
    const int wave = tid >> 6, lane = tid & 63;
    const int wm = (wave >> 1) * (BM / 2), wn = (wave & 1) * 64;
    const int l15 = lane & 15, quad = lane >> 4;
    const int l7 = l15 & 7;

    f32x4_t acc[MI][4];
    #pragma unroll
    for (int mi = 0; mi < MI; ++mi)
        #pragma unroll
        for (int ni = 0; ni < 4; ++ni)
            acc[mi][ni] = (f32x4_t){0.f, 0.f, 0.f, 0.f};

    auto stage = [&](int buf, int k0) {
        #pragma unroll
        for (int c = 0; c < BM / 32; ++c) {
            const int o = c * 4096 + tid * 16;
            const int row = o >> 7;
            const int g = ((o >> 4) & 7) ^ (row & 7);
            gload16(A + (size_t)(bm + row) * Kst + k0 + g * 8,
                    (char*)As[buf] + c * 4096 + wave * 1024);
        }
        #pragma unroll
        for (int c = 0; c < 4; ++c) {
            const int o = c * 4096 + tid * 16;
            const int row = o >> 7;
            const int g = ((o >> 4) & 7) ^ (row & 7);
            gload16(W + (size_t)(bn + row) * Kst + k0 + g * 8,
                    (char*)Bs[buf] + c * 4096 + wave * 1024);
        }
    };

    const int nIter = Ks >> 6;
    stage(0, 0);
    for (int it = 0; it < nIter; ++it) {
        const int buf = it & 1;
        __syncthreads();
        if (it + 1 < nIter) stage(buf ^ 1, (it + 1) * 64);
        #pragma unroll
        for (int h = 0; h < 2; ++h) {
            const int fg = (((h << 2) | quad) ^ l7) * 8;
            short8_t af[MI], bf[4];
            #pragma unroll
            for (int mi = 0; mi < MI; ++mi)
                af[mi] = *(const short8_t*)&As[buf][(wm + mi * 16 + l15) * 64 + fg];
            #pragma unroll
            for (int ni = 0; ni < 4; ++ni)
                bf[ni] = *(const short8_t*)&Bs[buf][(wn + ni * 16 + l15) * 64 + fg];
            #pragma unroll
            for (int mi = 0; mi < MI; ++mi)
                #pragma unroll
                for (int ni = 0; ni < 4; ++ni)
                    acc[mi][ni] = __builtin_amdgcn_mfma_f32_16x16x32_bf16(
                        af[mi], bf[ni], acc[mi][ni], 0, 0, 0);
        }
    }

    if (EPI == 4) {
        #pragma unroll
        for (int mi = 0; mi < MI; ++mi)
            #pragma unroll
            for (int r = 0; r < 4; ++r) {
                float s = 0.f;
                #pragma unroll
                for (int ni = 0; ni < 4; ++ni) {
                    const float x = acc[mi][ni][r];
                    s += x * x;
                }
                s += __shfl_xor(s, 1); s += __shfl_xor(s, 2);
                s += __shfl_xor(s, 4); s += __shfl_xor(s, 8);
                const float sc = 1.0f / fmaxf(sqrtf(s), 1e-6f);
                #pragma unroll
                for (int ni = 0; ni < 4; ++ni) acc[mi][ni][r] *= sc;
            }
    }

    const float a = (EPI == 1) ? alpha[0] : 0.f;
    #pragma unroll
    for (int mi = 0; mi < MI; ++mi) {
        #pragma unroll
        for (int ni = 0; ni < 4; ++ni) {
            const int n = bn + wn + ni * 16 + l15;
            const float bb = (EPI == 1) ? bias[n] : 0.f;
            #pragma unroll
            for (int r = 0; r < 4; ++r) {
                const int m = bm + wm + mi * 16 + (quad << 2) + r;
                const float x = acc[mi][ni][r];
                if (EPI == 4) {
                    out16[(size_t)m * N + n] = f2b(x);
                } else {
                    const size_t idx = (size_t)m * N + n;
                    outF[idx] = resF[idx] + a * (x + bb);
                }
            }
        }
    }
}

// ---------------------------------------------------------------------------
// Merged q-proj + kv-proj launch: 1-D grid 1536 with chunked XCD swizzle
// (r14). bx<16: kv-proj (MX fp8, BM=128, BK=128); bx>=16: q-proj (bf16).
// Pool 65536 B -> 2 blocks/CU.
// ---------------------------------------------------------------------------
__device__ __forceinline__ void kvproj_body(
    unsigned char* __restrict__ pool, int bx, int by, int tid,
    const unsigned char* __restrict__ A, const unsigned char* __restrict__ W,
    short* __restrict__ khd, short* __restrict__ vhd)
{
    constexpr int BM = 128, BK = 128, MI = 4;
    constexpr int Kst = 1024;
    auto AsBuf = [&](int b) { return pool + b * (BM * BK); };
    auto BsBuf = [&](int b) { return pool + 2 * BM * BK + b * (128 * BK); };
    const int bm = by * BM, bn = bx * 128;
    const int wave = tid >> 6, lane = tid & 63;
    const int wm = (wave >> 1) * (BM / 2), wn = (wave & 1) * 64;
    const int l15 = lane & 15, quad = lane >> 4;
    const int l7 = l15 & 7;

    f32x4_t acc[MI][4];
    #pragma unroll
    for (int mi = 0; mi < MI; ++mi)
        #pragma unroll
        for (int ni = 0; ni < 4; ++ni)
            acc[mi][ni] = (f32x4_t){0.f, 0.f, 0.f, 0.f};

    auto stage = [&](int buf, int k0) {
        #pragma unroll
        for (int c = 0; c < 4; ++c) {                 // A: 128 rows x 128 B
            const int o = c * 4096 + tid * 16;
            const int row = o >> 7;
            const int g = ((o >> 4) & 7) ^ (row & 7);
            gload16(A + (size_t)(bm + row) * Kst + k0 + g * 16,
                    (char*)AsBuf(buf) + c * 4096 + wave * 1024);
        }
        #pragma unroll
        for (int c = 0; c < 4; ++c) {                 // B: 128 rows x 128 B
            const int o = c * 4096 + tid * 16;
            const int row = o >> 7;
            const int g = ((o >> 4) & 7) ^ (row & 7);
            gload16(W + (size_t)(bn + row) * Kst + k0 + g * 16,
                    (char*)BsBuf(buf) + c * 4096 + wave * 1024);
        }
    };

    const int ga = ((quad << 1) ^ l7) << 4;           // k bytes quad*32..+15
    const int gb = (((quad << 1) | 1) ^ l7) << 4;     // k bytes quad*32+16..+31

    stage(0, 0);
    for (int it = 0; it < 8; ++it) {
        const int buf = it & 1;
        __syncthreads();
        if (it + 1 < 8) stage(buf ^ 1, (it + 1) * BK);
        int8v_t af[MI], bf[4];
        #pragma unroll
        for (int mi = 0; mi < MI; ++mi)
            af[mi] = ld32(AsBuf(buf) + (wm + mi * 16 + l15) * BK, ga, gb);
        #pragma unroll
        for (int ni = 0; ni < 4; ++ni)
            bf[ni] = ld32(BsBuf(buf) + (wn + ni * 16 + l15) * BK, ga, gb);
        #pragma unroll
        for (int mi = 0; mi < MI; ++mi)
            #pragma unroll
            for (int ni = 0; ni < 4; ++ni)
                acc[mi][ni] = __builtin_amdgcn_mfma_scale_f32_16x16x128_f8f6f4(
                    af[mi], bf[ni], acc[mi][ni], 0, 0, 0, SCL1, 0, SCL1);
    }

    const bool isK = (bn < 1024);
    if (isK) {                               // l2norm (scale-invariant) for k
        #pragma unroll
        for (int mi = 0; mi < MI; ++mi)
            #pragma unroll
            for (int r = 0; r < 4; ++r) {
                float s = 0.f;
                #pragma unroll
                for (int ni = 0; ni < 4; ++ni) {
                    const float x = acc[mi][ni][r];
                    s += x * x;
                }
                s += __shfl_xor(s, 1); s += __shfl_xor(s, 2);
                s += __shfl_xor(s, 4); s += __shfl_xor(s, 8);
                const float sc = 1.0f / fmaxf(sqrtf(s), 1e-6f);
                #pragma unroll
                for (int ni = 0; ni < 4; ++ni) acc[mi][ni][r] *= sc;
            }
    }
    __syncthreads();                         // all waves done with As/Bs
    short* Ct = (short*)pool;                // [128][136] bf16
    constexpr int LDC = 136;
    if (isK) {                               // Ct[m][n]
        #pragma unroll
        for (int mi = 0; mi < MI; ++mi)
            #pragma unroll
            for (int ni = 0; ni < 4; ++ni) {
                const int n = wn + ni * 16 + l15;
                #pragma unroll
                for (int r = 0; r < 4; ++r)
                    Ct[(wm + mi * 16 + (quad << 2) + r) * LDC + n] =
                        f2b(acc[mi][ni][r]);
            }
    } else {                                 // Ct[n][m], pack 4 m as short4
        #pragma unroll
        for (int mi = 0; mi < MI; ++mi)
            #pragma unroll
            for (int ni = 0; ni < 4; ++ni) {
                short4 pk;
                pk.x = f2b(acc[mi][ni][0] * OSC);
                pk.y = f2b(acc[mi][ni][1] * OSC);
                pk.z = f2b(acc[mi][ni][2] * OSC);
                pk.w = f2b(acc[mi][ni][3] * OSC);
                *(short4*)&Ct[(wn + ni * 16 + l15) * LDC +
                              wm + mi * 16 + (quad << 2)] = pk;
            }
    }
    __syncthreads();
    const int b_ = bm >> 11;
    const int kv0 = bm & 2047;
    #pragma unroll
    for (int p = 0; p < 8; ++p) {
        const int idx = p * 256 + tid;
        const int row = idx >> 4, ch = idx & 15;   // 128 rows x 16 chunks
        const short8_t v = *(const short8_t*)&Ct[row * LDC + ch * 8];
        if (isK) {            // row=m (kv), chunk covers n: 2 heads x 64 d
            const int hh = (bn >> 6) + (ch >> 3);
            *(short8_t*)&khd[(size_t)((b_ * 16 + hh) * 2048 + kv0 + row) * 64 +
                             (ch & 7) * 8] = v;
        } else {              // row=n (head,d), chunk covers m (kv)
            const int nn = bn - 1024 + row;
            *(short8_t*)&vhd[(size_t)((b_ * 16 + (nn >> 6)) * 64 +
                             (nn & 63)) * 2048 + kv0 + ch * 8] = v;
        }
    }
}

__device__ __forceinline__ void qproj_body(
    unsigned char* __restrict__ pool, int bx, int by, int tid,
    const short* __restrict__ A, const short* __restrict__ W,
    short* __restrict__ out16)
{
    constexpr int BM = 32, N = 1024, Kst = 1024;
    short* As = (short*)pool;                     // 2 bufs x BM*64 (8192 B)
    short* Bs = (short*)(pool + 8192);            // 2 bufs x 128*64 (32768 B)
    const int bm = by * BM, bn = bx * 128;
    const int wave = tid >> 6, lane = tid & 63;
    const int wm = (wave >> 1) * 16, wn = (wave & 1) * 64;
    const int l15 = lane & 15, quad = lane >> 4;
    const int l7 = l15 & 7;

    f32x4_t acc[4];
    #pragma unroll
    for (int ni = 0; ni < 4; ++ni) acc[ni] = (f32x4_t){0.f, 0.f, 0.f, 0.f};

    auto stage = [&](int buf, int k0) {
        {
            const int o = tid * 16;               // A: 32 rows x 128 B
            const int row = o >> 7;
            const int g = ((o >> 4) & 7) ^ (row & 7);
            gload16(A + (size_t)(bm + row) * Kst + k0 + g * 8,
                    (char*)As + buf * 4096 + wave * 1024);
        }
        #pragma unroll
        for (int c = 0; c < 4; ++c) {             // B: 128 rows x 128 B
            const int o = c * 4096 + tid * 16;
            const int row = o >> 7;
            const int g = ((o >> 4) & 7) ^ (row & 7);
            gload16(W + (size_t)(bn + row) * Kst + k0 + g * 8,
                    (char*)Bs + buf * 16384 + c * 4096 + wave * 1024);
        }
    };

    stage(0, 0);
    for (int it = 0; it < 16; ++it) {
        const int buf = it & 1;
        __syncthreads();
        if (it + 1 < 16) stage(buf ^ 1, (it + 1) * 64);
        #pragma unroll
        for (int h = 0; h < 2; ++h) {
            const int fg = (((h << 2) | quad) ^ l7) * 8;
            const short8_t af =
                *(const short8_t*)&As[buf * 2048 + (wm + l15) * 64 + fg];
            short8_t bf[4];
            #pragma unroll
            for (int ni = 0; ni < 4; ++ni)
                bf[ni] = *(const short8_t*)&Bs[buf * 8192 +
                                               (wn + ni * 16 + l15) * 64 + fg];
            #pragma unroll
            for (int ni = 0; ni < 4; ++ni)
                acc[ni] = __builtin_amdgcn_mfma_f32_16x16x32_bf16(
                    af, bf[ni], acc[ni], 0, 0, 0);
        }
    }

    // l2norm over each 64-col head slice (wn selects head half)
    #pragma unroll
    for (int r = 0; r < 4; ++r) {
        float s = 0.f;
        #pragma unroll
        for (int ni = 0; ni < 4; ++ni) {
            const float x = acc[ni][r];
            s += x * x;
        }
        s += __shfl_xor(s, 1); s += __shfl_xor(s, 2);
        s += __shfl_xor(s, 4); s += __shfl_xor(s, 8);
        const float sc = 1.0f / fmaxf(sqrtf(s), 1e-6f);
        #pragma unroll
        for (int ni = 0; ni < 4; ++ni) acc[ni][r] *= sc;
    }
    #pragma unroll
    for (int ni = 0; ni < 4; ++ni) {
        const int n = bn + wn + ni * 16 + l15;
        #pragma unroll
        for (int r = 0; r < 4; ++r) {
            const int m = bm + wm + (quad << 2) + r;
            out16[(size_t)m * N + n] = f2b(acc[ni][r]);
        }
    }
}

__global__ __launch_bounds__(256, 2) void qkv_kernel(
    const unsigned char* __restrict__ kvn8, const unsigned char* __restrict__ Wkv8,
    short* __restrict__ khd, short* __restrict__ vhd,
    const short* __restrict__ qn, const short* __restrict__ Wq_b,
    short* __restrict__ qbuf)
{
    __shared__ __attribute__((aligned(16))) unsigned char pool[65536];
    const int id = blockIdx.x;               // 0..1535
    const int xcd = id & 7, slot = id >> 3;  // chunked XCD swizzle (r14)
    const int by = xcd * 8 + (slot & 7);     // 0..63: band per XCD
    const int bx = slot >> 3;                // 0..23
    const int tid = threadIdx.x;
    if (bx < 16) kvproj_body(pool, bx, by, tid, kvn8, Wkv8, khd, vhd);
    else         qproj_body(pool, bx - 16, by, tid, qn, Wq_b, qbuf);
}

// ---------------------------------------------------------------------------
// MX fp8 GEMM (fc1, fc2): BN=128, BK=128, K=128 scaled MFMA (unit scales),
// dbuf single-barrier. 32 B fragments via two swizzled ds_read_b128.
// EPI: 2 fc1: fp8 out8 = gelu(acc*OSC + bias)   [LDS-staged coalesced 16B]
//      7 fc2 split-K partial: out16 + z*M*N = bf16(acc)  (raw x16 scale)
// ---------------------------------------------------------------------------
template <int EPI, int BM>
__global__ __launch_bounds__(256, 2) void gemm_f8_kernel(
    const unsigned char* __restrict__ A, const unsigned char* __restrict__ W,
    int M, int N, int Ks, int Kst,
    const float* __restrict__ bias,
    unsigned char* __restrict__ out8,
    short* __restrict__ out16,
    float* __restrict__ outF)
{
    constexpr int MI = BM / 32;
    constexpr int BK = 128;
    constexpr int STG = 2 * BM * BK + 2 * 128 * BK;
    constexpr int EPIB = (EPI == 2) ? BM * 144 : 0;
    constexpr int POOL = (STG > EPIB) ? STG : EPIB;
    __shared__ __attribute__((aligned(16))) unsigned char pool[POOL];
    auto AsBuf = [&](int b) { return pool + b * (BM * BK); };
    auto BsBuf = [&](int b) { return pool + 2 * BM * BK + b * (128 * BK); };
    const int bm = blockIdx.y * BM, bn = blockIdx.x * 128;
    const size_t kbase = (size_t)blockIdx.z * Ks;
    const int tid = threadIdx.x;
    const int wave = tid >> 6, lane = tid & 63;
    const int wm = (wave >> 1) * (BM / 2), wn = (wave & 1) * 64;
    const int l15 = lane & 15, quad = lane >> 4;
    const int l7 = l15 & 7;

    f32x4_t acc[MI][4];
    #pragma unroll
    for (int mi = 0; mi < MI; ++mi)
        #pragma unroll
        for (int ni = 0; ni < 4; ++ni)
            acc[mi][ni] = (f32x4_t){0.f, 0.f, 0.f, 0.f};

    auto stage = [&](int buf, int k0) {
        #pragma unroll
        for (int c = 0; c < BM * BK / 4096; ++c) {    // A: BM rows x 128 B
            const int o = c * 4096 + tid * 16;
            const int row = o >> 7;
            const int g = ((o >> 4) & 7) ^ (row & 7);
            gload16(A + (size_t)(bm + row) * Kst + kbase + k0 + g * 16,
                    (char*)AsBuf(buf) + c * 4096 + wave * 1024);
        }
        #pragma unroll
        for (int c = 0; c < 4; ++c) {                 // B: 128 rows x 128 B
            const int o = c * 4096 + tid * 16;
            const int row = o >> 7;
            const int g = ((o >> 4) & 7) ^ (row & 7);
            gload16(W + (size_t)(bn + row) * Kst + kbase + k0 + g * 16,
                    (char*)BsBuf(buf) + c * 4096 + wave * 1024);
        }
    };

    const int ga = ((quad << 1) ^ l7) << 4;
    const int gb = (((quad << 1) | 1) ^ l7) << 4;

    const int nIter = Ks >> 7;
    stage(0, 0);
    for (int it = 0; it < nIter; ++it) {
        const int buf = it & 1;
        __syncthreads();
        if (it + 1 < nIter) stage(buf ^ 1, (it + 1) * BK);
        int8v_t af[MI], bf[4];
        #pragma unroll
        for (int mi = 0; mi < MI; ++mi)
            af[mi] = ld32(AsBuf(buf) + (wm + mi * 16 + l15) * BK, ga, gb);
        #pragma unroll
        for (int ni = 0; ni < 4; ++ni)
            bf[ni] = ld32(BsBuf(buf) + (wn + ni * 16 + l15) * BK, ga, gb);
        #pragma unroll
        for (int mi = 0; mi < MI; ++mi)
            #pragma unroll
            for (int ni = 0; ni < 4; ++ni)
                acc[mi][ni] = __builtin_amdgcn_mfma_scale_f32_16x16x128_f8f6f4(
                    af[mi], bf[ni], acc[mi][ni], 0, 0, 0, SCL1, 0, SCL1);
    }

    if (EPI == 2) {                            // fc1 + GELU, LDS-staged fp8
        __syncthreads();
        unsigned char* C8 = (unsigned char*)pool;   // [BM][144] fp8
        constexpr int LDC8 = 144;
        #pragma unroll
        for (int mi = 0; mi < MI; ++mi)
            #pragma unroll
            for (int ni = 0; ni < 4; ++ni) {
                const int n = wn + ni * 16 + l15;
                const float bb = bias[bn + n];
                #pragma unroll
                for (int r = 0; r < 4; ++r) {
                    const float t = acc[mi][ni][r] * OSC + bb;
                    C8[(wm + mi * 16 + (quad << 2) + r) * LDC8 + n] =
                        f2f8(0.5f * t * (1.0f + erff(t * 0.70710678118f)));
                }
            }
        __syncthreads();
        #pragma unroll
        for (int p = 0; p < MI; ++p) {
            const int idx = p * 256 + tid;
            const int row = idx >> 3, ch = idx & 7;
            const f32x4_t v = *(const f32x4_t*)&C8[row * LDC8 + ch * 16];
            *(f32x4_t*)&out8[(size_t)(bm + row) * N + bn + ch * 16] = v;
        }
        return;
    }

    // EPI == 7: fc2 split-K bf16 partials (raw x16 scale; reduce applies OSC)
    #pragma unroll
    for (int mi = 0; mi < MI; ++mi) {
        #pragma unroll
        for (int ni = 0; ni < 4; ++ni) {
            const int n = bn + wn + ni * 16 + l15;
            #pragma unroll
            for (int r = 0; r < 4; ++r) {
                const int m = bm + wm + mi * 16 + (quad << 2) + r;
                out16[(size_t)blockIdx.z * M * N + (size_t)m * N + n] =
                    f2b(acc[mi][ni][r]);
            }
        }
    }
}

// ---------------------------------------------------------------------------
// Split-K reduce for fc2 (bf16 partials):
// out = resF + alpha*((p0+p1+p2+p3)*OSC + bias).
// ---------------------------------------------------------------------------
__global__ __launch_bounds__(256) void reduce4_kernel(
    const short* __restrict__ parts, const float* __restrict__ resF,
    const float* __restrict__ bias, const float* __restrict__ alpha,
    float* __restrict__ out)
{
    const int i = blockIdx.x * 256 + threadIdx.x;   // short4 idx over 2048x1024
    const size_t MN4 = (size_t)2048 * 1024 / 4;
    const float a = alpha[0];
    const float4 b4 = ((const float4*)bias)[i & 255];
    const short4 p0 = ((const short4*)parts)[i];
    const short4 p1 = ((const short4*)parts)[MN4 + i];
    const short4 p2 = ((const short4*)parts)[2 * MN4 + i];
    const short4 p3 = ((const short4*)parts)[3 * MN4 + i];
    const float4 rv = ((const float4*)resF)[i];
    float4 o;
    o.x = rv.x + a * ((b2f(p0.x) + b2f(p1.x) + b2f(p2.x) + b2f(p3.x)) * OSC + b4.x);
    o.y = rv.y + a * ((b2f(p0.y) + b2f(p1.y) + b2f(p2.y) + b2f(p3.y)) * OSC + b4.y);
    o.z = rv.z + a * ((b2f(p0.z) + b2f(p1.z) + b2f(p2.z) + b2f(p3.z)) * OSC + b4.z);
    o.w = rv.w + a * ((b2f(p0.w) + b2f(p1.w) + b2f(p2.w) + b2f(p3.w)) * OSC + b4.w);
    ((float4*)out)[i] = o;
}

// ---------------------------------------------------------------------------
// Attention (r10 + r13 bf16 partials + r14 setprio): KV-split x2, K/V
// LDS-staged, zero cross-lane softmax. Grid (h=16, b=4, qt*2+sp=16) = 1024
// blocks; LDS 32768 B -> 4 blocks/CU. Same-head blocks land on one XCD.
// Swapped QK -> P is the 16x16x16 MFMA A-fragment; PV + row-sum via mfma16.
// ---------------------------------------------------------------------------
__global__ __launch_bounds__(256, 4) void attn_kernel(
    const short* __restrict__ q, const short* __restrict__ khd,
    const short* __restrict__ vhd, short* __restrict__ o0,
    short* __restrict__ o1, float* __restrict__ lpart)
{
    const int h  = blockIdx.x;        // 0..15
    const int b  = blockIdx.y;        // 0..3
    const int qt = blockIdx.z >> 1;   // 0..7
    const int sp = blockIdx.z & 1;    // kv-split 0..1
    const int tid = threadIdx.x;
    const int wave = tid >> 6, lane = tid & 63;
    const int l15 = lane & 15, quad = lane >> 4;
    const int q0 = qt * 64 + wave * 16;
    const int t0 = sp * 16;           // first KV tile for this split

    __shared__ __attribute__((aligned(16))) short Ks[2][4096];
    __shared__ __attribute__((aligned(16))) short Vs[2][4096];

    const short* qbase = q + (size_t)(b * 512 + q0 + l15) * 1024 + h * 64 + quad * 8;
    const short8_t aq0 = *(const short8_t*)(qbase);
    const short8_t aq1 = *(const short8_t*)(qbase + 32);

    const short* kbase = khd + (size_t)(b * 16 + h) * 2048 * 64;  // [2048][64]
    const short* vbase = vhd + (size_t)(b * 16 + h) * 64 * 2048;  // [64][2048]

    const int swz = l15 & 7;
    const int g0 = (quad ^ swz) * 8;
    const int g1 = ((quad ^ swz) ^ 4) * 8;

    auto stage = [&](int buf, int t) {
        #pragma unroll
        for (int c = 0; c < 2; ++c) {
            const int o = c * 4096 + tid * 16;
            const int row = o >> 7;              // 64 rows x 128 B
            const int g = ((o >> 4) & 7) ^ (row & 7);
            gload16(kbase + (size_t)(t * 64 + row) * 64 + g * 8,
                    (char*)Ks[buf] + c * 4096 + wave * 1024);
            gload16(vbase + (size_t)row * 2048 + t * 64 + g * 8,
                    (char*)Vs[buf] + c * 4096 + wave * 1024);
        }
    };

    const short4_t ones4 = {(short)0x3F80, (short)0x3F80,
                            (short)0x3F80, (short)0x3F80};   // 4 x bf16 1.0

    f32x4_t oacc[4];
    #pragma unroll
    for (int u = 0; u < 4; ++u) oacc[u] = (f32x4_t){0.f, 0.f, 0.f, 0.f};
    f32x4_t lacc = (f32x4_t){0.f, 0.f, 0.f, 0.f};

    stage(0, t0);
    for (int tt = 0; tt < 16; ++tt) {
        const int buf = tt & 1;
        __syncthreads();
        if (tt + 1 < 16) stage(buf ^ 1, t0 + tt + 1);

        // swapped QK^T: s[ss] holds P-pre[kv=ss*16+quad*4+r][q=l15]
        f32x4_t s[4];
        __builtin_amdgcn_s_setprio(1);
        #pragma unroll
        for (int ss = 0; ss < 4; ++ss) {
            const int R = ss * 16 + l15;
            const short8_t bk0 = *(const short8_t*)&Ks[buf][R * 64 + g0];
            const short8_t bk1 = *(const short8_t*)&Ks[buf][R * 64 + g1];
            f32x4_t a = (f32x4_t){0.f, 0.f, 0.f, 0.f};
            a = __builtin_amdgcn_mfma_f32_16x16x32_bf16(bk0, aq0, a, 0, 0, 0);
            a = __builtin_amdgcn_mfma_f32_16x16x32_bf16(bk1, aq1, a, 0, 0, 0);
            s[ss] = a;
        }
        __builtin_amdgcn_s_setprio(0);
        // exp + pack: pa[ss] = A-fragment P^T[q=l15][kv local quad*4+j]
        short4_t pa[4];
        #pragma unroll
        for (int ss = 0; ss < 4; ++ss) {
            const float p0 = __expf(s[ss][0] * 0.5f);
            const float p1 = __expf(s[ss][1] * 0.5f);
            const float p2 = __expf(s[ss][2] * 0.5f);
            const float p3 = __expf(s[ss][3] * 0.5f);
            union { unsigned w[2]; short4_t v; } u_;
            u_.w[0] = cvt_pk_bf16(p0, p1);
            u_.w[1] = cvt_pk_bf16(p2, p3);
            pa[ss] = u_.v;
        }
        __builtin_amdgcn_s_setprio(1);
        // row-sum: l[q] += sum_kv P
        #pragma unroll
        for (int ss = 0; ss < 4; ++ss)
            lacc = __builtin_amdgcn_mfma_f32_16x16x16bf16_1k(
                pa[ss], ones4, lacc, 0, 0, 0);
        // PV: oacc[u] += P^T x V, K=16 per ss; V frag = ds_read_b64
        #pragma unroll
        for (int ss = 0; ss < 4; ++ss) {
            const int ch = (((ss * 2 + (quad >> 1)) ^ swz) << 3) + ((quad & 1) << 2);
            #pragma unroll
            for (int u = 0; u < 4; ++u) {
                const short4_t bv =
                    *(const short4_t*)&Vs[buf][(u * 16 + l15) * 64 + ch];
                oacc[u] = __builtin_amdgcn_mfma_f32_16x16x16bf16_1k(
                    pa[ss], bv, oacc[u], 0, 0, 0);
            }
        }
        __builtin_amdgcn_s_setprio(0);
    }

    // raw bf16 partial writes (no normalization here)
    short* ob = sp ? o1 : o0;
    float* lb = lpart + (size_t)sp * 2048 * 16;
    #pragma unroll
    for (int u = 0; u < 4; ++u)
        #pragma unroll
        for (int r = 0; r < 4; ++r)
            ob[(size_t)(b * 512 + q0 + quad * 4 + r) * 1024 + h * 64 + u * 16 + l15] =
                f2b(oacc[u][r]);
    if (l15 == 0) {
        #pragma unroll
        for (int r = 0; r < 4; ++r)
            lb[(size_t)(b * 512 + q0 + quad * 4 + r) * 16 + h] = lacc[r];
    }
}

// ---------------------------------------------------------------------------
// Combine the two KV-split bf16 partials: ctx = (o0+o1)/(l0+l1) -> bf16.
// ---------------------------------------------------------------------------
__global__ __launch_bounds__(256) void attn_combine_kernel(
    const short* __restrict__ o0, const short* __restrict__ o1,
    const float* __restrict__ lpart, short* __restrict__ ctx)
{
    const int i = blockIdx.x * 256 + threadIdx.x;   // short4 idx over 2048x1024
    const int row = i >> 8;
    const int h = (i & 255) >> 4;
    const float l = lpart[row * 16 + h] + lpart[2048 * 16 + row * 16 + h];
    const float inv = 1.0f / l;
    const short4 a4 = ((const short4*)o0)[i];
    const short4 c4 = ((const short4*)o1)[i];
    short4 o;
    o.x = f2b((b2f(a4.x) + b2f(c4.x)) * inv);
    o.y = f2b((b2f(a4.y) + b2f(c4.y)) * inv);
    o.z = f2b((b2f(a4.z) + b2f(c4.z)) * inv);
    o.w = f2b((b2f(a4.w) + b2f(c4.w)) * inv);
    ((short4*)ctx)[i] = o;
}

// ---------------------------------------------------------------------------
extern "C" void kernel_launch(void* const* d_in, const int* in_sizes, int n_in,
                              void* d_out, int out_size, void* d_ws, size_t ws_size,
                              hipStream_t stream)
{
    const float* q_tokens  = (const float*)d_in[0];
    const float* kv_tokens = (const float*)d_in[1];
    const float* q_ln_w    = (const float*)d_in[2];
    const float* q_ln_b    = (const float*)d_in[3];
    const float* kv_ln_w   = (const float*)d_in[4];
    const float* kv_ln_b   = (const float*)d_in[5];
    const float* mlp_ln_w  = (const float*)d_in[6];
    const float* mlp_ln_b  = (const float*)d_in[7];
    const float* Wq        = (const float*)d_in[8];
    const float* Wk        = (const float*)d_in[9];
    const float* Wv        = (const float*)d_in[10];
    const float* Wo        = (const float*)d_in[11];
    const float* bo        = (const float*)d_in[12];
    const float* fc1_w     = (const float*)d_in[13];
    const float* fc1_b     = (const float*)d_in[14];
    const float* fc2_w     = (const float*)d_in[15];
    const float* fc2_b     = (const float*)d_in[16];
    const float* alpha_attn = (const float*)d_in[17];
    const float* alpha_mlp  = (const float*)d_in[18];

    char* ws = (char*)d_ws;
    const size_t MB = (size_t)1 << 20;
    short* khd    = (short*)(ws);             // 16 MB [4,16,2048,64]; dead after attn
    short* vhd    = (short*)(ws + 16 * MB);   // 16 MB [4,16,64,2048]; dead after attn
    short* parts  = (short*)(ws);             // 16 MB fc2 bf16 partials (overlays khd)
    unsigned char* kvn8 = (unsigned char*)(ws + 32 * MB); // 8 MB; dead after kv-gemm
    short* attn_o0 = (short*)(ws + 32 * MB);  //    overlays kvn8: 4 MB bf16 partial
    unsigned char* h1   = (unsigned char*)(ws + 32 * MB); //  overlays kvn8: 8 MB fp8
    short* qn     = (short*)(ws + 40 * MB);   //  4 MB [2048,1024] bf16
    short* qbuf   = (short*)(ws + 44 * MB);   //  4 MB [2048,1024] bf16 (l2-normed q)
    short* ctx    = (short*)(ws + 48 * MB);   //  4 MB [2048,1024] bf16
    float* aout   = (float*)(ws + 52 * MB);   //  8 MB [2048,1024] fp32
    short* attn_o1 = (short*)(ws + 52 * MB);  //    overlays aout: 4 MB bf16 partial
    unsigned char* hn8 = (unsigned char*)(ws + 60 * MB);  // 2 MB fp8
    float* attn_l  = (float*)(ws + 60 * MB);  //    overlays hn8: 256 KB [2,2048,16]
    short* Wq_b   = (short*)(ws + 62 * MB);   //  2 MB bf16
    short* Wo_b   = (short*)(ws + 64 * MB);   //  2 MB bf16
    unsigned char* Wkv8  = (unsigned char*)(ws + 66 * MB); // 2 MB fp8 stacked
    unsigned char* fc1_8 = (unsigned char*)(ws + 68 * MB); // 4 MB fp8
    unsigned char* fc2_8 = (unsigned char*)(ws + 72 * MB); // 4 MB fp8

    // 0) fused: q-LN(bf16) + kv-LN(fp8) + weight casts
    prep_kernel<<<22528, 256, 0, stream>>>(
        q_tokens, kv_tokens, q_ln_w, q_ln_b, kv_ln_w, kv_ln_b, qn, kvn8,
        Wq, Wo, Wk, Wv, fc1_w, fc2_w,
        Wq_b, Wo_b, Wkv8, fc1_8, fc2_8);

    // 1) merged q-proj (+l2norm) and kv-proj (MX fp8, fused l2norm/scatter)
    qkv_kernel<<<1536, 256, 0, stream>>>(
        kvn8, Wkv8, khd, vhd, qn, Wq_b, qbuf);

    // 2) Attention: KV-split x2, bf16 partials; combine normalizes -> ctx
    attn_kernel<<<dim3(16, 4, 16), 256, 0, stream>>>(
        qbuf, khd, vhd, attn_o0, attn_o1, attn_l);
    attn_combine_kernel<<<2048, 256, 0, stream>>>(attn_o0, attn_o1, attn_l, ctx);

    // 3) Out-proj + residual (bf16, BM=32)
    gemm_bt_kernel<1, 32><<<dim3(8, 64), 256, 0, stream>>>(
        ctx, Wo_b, 2048, 1024, 1024, 1024, bo, q_tokens, alpha_attn, nullptr, aout);

    // 4) MLP LN -> fp8
    ln8_kernel<<<2048, 256, 0, stream>>>(aout, mlp_ln_w, mlp_ln_b, hn8);

    // 5) fc1 (MX fp8, BM=64) + exact GELU -> fp8 h1
    gemm_f8_kernel<2, 64><<<dim3(32, 32), 256, 0, stream>>>(
        hn8, fc1_8, 2048, 4096, 1024, 1024, fc1_b, h1, nullptr, nullptr);

    // 6) fc2 (MX fp8, BM=64) split-K x4 -> bf16 partials, reduce -> d_out
    gemm_f8_kernel<7, 64><<<dim3(8, 32, 4), 256, 0, stream>>>(
        h1, fc2_8, 2048, 1024, 1024, 4096, nullptr, nullptr, parts, nullptr);
    reduce4_kernel<<<2048, 256, 0, stream>>>(parts, aout, fc2_b, alpha_mlp,
                                             (float*)d_out);
}

// Round 11
// 278.480 us; speedup vs baseline: 1.0404x; 1.0404x over previous
//
#include <hip/hip_runtime.h>

// ---------------------------------------------------------------------------
// CrossAttentionBlockPatched: B=4, Lq=512, Lkv=2048, DIM=1024, H=16, hd=64,
// MLP_HIDDEN=4096, TAU=2.0, EPS=1e-6. fp32 in/out.
// kv-proj: MX-scaled fp8 K=128 MFMA (unit scales; r15 — measured faster).
// fc1/fc2: non-scaled fp8 K=32, BK=64, 4 blk/CU (r14 — MX port of these
// REGRESSED ~9us: too few K-iters to amortize + residency loss; reverted).
// Small GEMMs (q-proj, Wo) + attention: bf16 MFMA. fp32 accumulation.
// r6..r15 history in prior rounds. r16 = r14 + MX kv-proj only.
// ---------------------------------------------------------------------------

typedef __attribute__((ext_vector_type(8))) short short8_t;   // 8 x bf16
typedef __attribute__((ext_vector_type(4))) short short4_t;   // 4 x bf16
typedef __attribute__((ext_vector_type(4))) float f32x4_t;    // 4 x fp32
typedef __attribute__((ext_vector_type(8))) int int8v_t;      // 32 x fp8
typedef __attribute__((ext_vector_type(4))) int int4v_t;      // 16 B

#define WSCALE 16.0f
#define OSC (1.0f / 16.0f)
#define SCL1 127   // e8m0 exponent 127 -> scale 1.0

__device__ __forceinline__ float b2f(short s) {
    union { float f; unsigned u; } c;
    c.u = ((unsigned)(unsigned short)s) << 16;
    return c.f;
}
__device__ __forceinline__ short f2b(float f) {
    union { float f; unsigned u; } c;
    c.f = f;
    unsigned u = c.u;
    unsigned r = (u + 0x7FFFu + ((u >> 16) & 1u)) >> 16;
    return (short)r;
}
__device__ __forceinline__ unsigned cvt_pk_bf16(float lo, float hi) {
    unsigned r;
    asm("v_cvt_pk_bf16_f32 %0, %1, %2" : "=v"(r) : "v"(lo), "v"(hi));
    return r;
}
__device__ __forceinline__ unsigned f2f8_pk4(float a, float b, float c, float d) {
    int lo = __builtin_amdgcn_cvt_pk_fp8_f32(a, b, 0, false);
    return (unsigned)__builtin_amdgcn_cvt_pk_fp8_f32(c, d, lo, true);
}
__device__ __forceinline__ unsigned char f2f8(float a) {
    return (unsigned char)(__builtin_amdgcn_cvt_pk_fp8_f32(a, a, 0, false) & 0xff);
}

// async global -> LDS, 16 B per lane; lds base must be wave-uniform.
__device__ __forceinline__ void gload16(const void* g, void* l) {
    __builtin_amdgcn_global_load_lds(
        (const __attribute__((address_space(1))) void*)g,
        (__attribute__((address_space(3))) void*)l, 16, 0, 0);
}

// 32 B fp8 fragment from two swizzled 16 B LDS groups.
__device__ __forceinline__ int8v_t ld32(const unsigned char* base, int g0, int g1) {
    const int4v_t lo = *(const int4v_t*)(base + g0);
    const int4v_t hi = *(const int4v_t*)(base + g1);
    int8v_t r;
    r[0] = lo[0]; r[1] = lo[1]; r[2] = lo[2]; r[3] = lo[3];
    r[4] = hi[0]; r[5] = hi[1]; r[6] = hi[2]; r[7] = hi[3];
    return r;
}

// ---------------------------------------------------------------------------
// LayerNorm row helper: fp32 in; OUT8=0 -> bf16 out, OUT8=1 -> fp8 out.
// ---------------------------------------------------------------------------
template <int OUT8>
__device__ __forceinline__ void ln_row(
    const float* __restrict__ x, const float* __restrict__ w,
    const float* __restrict__ bia, void* __restrict__ y,
    int row, int tid, float* red)
{
    const float4 t = *(const float4*)(x + (size_t)row * 1024 + tid * 4);
    float v[4] = {t.x, t.y, t.z, t.w};
    float s = v[0] + v[1] + v[2] + v[3];
    float s2 = v[0]*v[0] + v[1]*v[1] + v[2]*v[2] + v[3]*v[3];
    #pragma unroll
    for (int off = 1; off < 64; off <<= 1) {
        s  += __shfl_xor(s, off);
        s2 += __shfl_xor(s2, off);
    }
    const int wave = tid >> 6, lane = tid & 63;
    if (lane == 0) { red[wave] = s; red[4 + wave] = s2; }
    __syncthreads();
    s  = red[0] + red[1] + red[2] + red[3];
    s2 = red[4] + red[5] + red[6] + red[7];
    const float mu  = s * (1.0f / 1024.0f);
    const float var = s2 * (1.0f / 1024.0f) - mu * mu;
    const float rstd = rsqrtf(var + 1e-6f);
    const float4 wv = *(const float4*)(w + tid * 4);
    const float4 bv = *(const float4*)(bia + tid * 4);
    const float o0 = (v[0] - mu) * rstd * wv.x + bv.x;
    const float o1 = (v[1] - mu) * rstd * wv.y + bv.y;
    const float o2 = (v[2] - mu) * rstd * wv.z + bv.z;
    const float o3 = (v[3] - mu) * rstd * wv.w + bv.w;
    if (OUT8) {
        ((unsigned*)y)[(size_t)row * 256 + tid] = f2f8_pk4(o0, o1, o2, o3);
    } else {
        short4 o;
        o.x = f2b(o0); o.y = f2b(o1); o.z = f2b(o2); o.w = f2b(o3);
        *(short4*)((short*)y + (size_t)row * 1024 + tid * 4) = o;
    }
}

// ---------------------------------------------------------------------------
// prep: q-LN -> bf16 (blocks 0..2047), kv-LN -> fp8 (2048..10239), weight
// casts (10240..22527): Wq,Wo -> bf16; Wkv,fc1,fc2 -> fp8 scaled x16.
// ---------------------------------------------------------------------------
__global__ __launch_bounds__(256) void prep_kernel(
    const float* __restrict__ qt, const float* __restrict__ kvt,
    const float* __restrict__ qlw, const float* __restrict__ qlb,
    const float* __restrict__ klw, const float* __restrict__ klb,
    short* __restrict__ qn, unsigned char* __restrict__ kvn8,
    const float* __restrict__ Wq, const float* __restrict__ Wo,
    const float* __restrict__ Wk, const float* __restrict__ Wv,
    const float* __restrict__ fc1w, const float* __restrict__ fc2w,
    short* __restrict__ Wq_b, short* __restrict__ Wo_b,
    unsigned char* __restrict__ Wkv8,
    unsigned char* __restrict__ fc1_8, unsigned char* __restrict__ fc2_8)
{
    __shared__ float red[8];
    const int bid = blockIdx.x, tid = threadIdx.x;
    if (bid < 2048) {
        ln_row<0>(qt, qlw, qlb, qn, bid, tid, red);
    } else if (bid < 10240) {
        ln_row<1>(kvt, klw, klb, kvn8, bid - 2048, tid, red);
    } else {
        int f = (bid - 10240) * 256 + tid;   // float4 index, total 3145728
        if (f < 524288) {                    // Wq, Wo -> bf16
            const float* src = (f < 262144) ? Wq : Wo;
            short* dst = (f < 262144) ? Wq_b : Wo_b;
            const int off = f & 262143;
            const float4 v = ((const float4*)src)[off];
            short4 o;
            o.x = f2b(v.x); o.y = f2b(v.y); o.z = f2b(v.z); o.w = f2b(v.w);
            ((short4*)dst)[off] = o;
        } else {                             // fp8 x16
            const float* src; unsigned* dst; int off;
            if (f < 1048576) {
                off = f - 524288;
                src = (off < 262144) ? Wk : Wv;
                dst = (unsigned*)Wkv8;
                if (off >= 262144) { src = Wv; }
                const int so = (off < 262144) ? off : off - 262144;
                const float4 v = ((const float4*)src)[so];
                dst[off] = f2f8_pk4(v.x * WSCALE, v.y * WSCALE,
                                    v.z * WSCALE, v.w * WSCALE);
                return;
            } else if (f < 2097152) {
                off = f - 1048576; src = fc1w; dst = (unsigned*)fc1_8;
            } else {
                off = f - 2097152; src = fc2w; dst = (unsigned*)fc2_8;
            }
            const float4 v = ((const float4*)src)[off];
            dst[off] = f2f8_pk4(v.x * WSCALE, v.y * WSCALE,
                                v.z * WSCALE, v.w * WSCALE);
        }
    }
}

// ---------------------------------------------------------------------------
// Standalone LN for MLP: fp32 in, fp8 out.
// ---------------------------------------------------------------------------
__global__ __launch_bounds__(256) void ln8_kernel(
    const float* __restrict__ x, const float* __restrict__ w,
    const float* __restrict__ bia, unsigned char* __restrict__ y)
{
    __shared__ float red[8];
    ln_row<1>(x, w, bia, y, blockIdx.x, threadIdx.x, red);
}

// ---------------------------------------------------------------------------
// bf16 GEMM (Wo): BN=128, BK=64, dbuf single-barrier K-loop,
// 128 B LDS rows + 3-bit XOR swizzle. Wave tile (BM/2)x64.
// EPI: 1 outF = resF + alpha*(acc+bias); 4 l2norm(64-col head) bf16 out.
// ---------------------------------------------------------------------------
template <int EPI, int BM>
__global__ __launch_bounds__(256) void gemm_bt_kernel(
    const short* __restrict__ A, const short* __restrict__ W,
    int M, int N, int Ks, int Kst,
    const float* __restrict__ bias,
    const float* __restrict__ resF,
    const float* __restrict__ alpha,
    short* __restrict__ out16,
    float* __restrict__ outF)
{
    constexpr int MI = (BM + 31) / 32;
    __shared__ __attribute__((aligned(16))) short As[2][BM * 64];
    __shared__ __attribute__((aligned(16))) short Bs[2][128 * 64];
    const int bm = blockIdx.y * BM, bn = blockIdx.x * 128;
    const int tid = threadIdx.x;
    const int wave = tid >> 6, lane = tid & 63;
    const int wm = (wave >> 1) * (BM / 2), wn = (wave & 1) * 64;
    const int l15 = lane & 15, quad = lane >> 4;
    const int l7 = l15 & 7;

    f32x4_t acc[MI][4];
    #pragma unroll
    for (int mi = 0; mi < MI; ++mi)
        #pragma unroll
        for (int ni = 0; ni < 4; ++ni)
            acc[mi][ni] = (f32x4_t){0.f, 0.f, 0.f, 0.f};

    auto stage = [&](int buf, int k0) {
        #pragma unroll
        for (int c = 0; c < BM / 32; ++c) {
            const int o = c * 4096 + tid * 16;
            const int row = o >> 7;
            const int g = ((o >> 4) & 7) ^ (row & 7);
            gload16(A + (size_t)(bm + row) * Kst + k0 + g * 8,
                    (char*)As[buf] + c * 4096 + wave * 1024);
        }
        #pragma unroll
        for (int c = 0; c < 4; ++c) {
            const int o = c * 4096 + tid * 16;
            const int row = o >> 7;
            const int g = ((o >> 4) & 7) ^ (row & 7);
            gload16(W + (size_t)(bn + row) * Kst + k0 + g * 8,
                    (char*)Bs[buf] + c * 4096 + wave * 1024);
        }
    };

    const int nIter = Ks >> 6;
    stage(0, 0);
    for (int it = 0; it < nIter; ++it) {
        const int buf = it & 1;
        __syncthreads();
        if (it + 1 < nIter) stage(buf ^ 1, (it + 1) * 64);
        #pragma unroll
        for (int h = 0; h < 2; ++h) {
            const int fg = (((h << 2) | quad) ^ l7) * 8;
            short8_t af[MI], bf[4];
            #pragma unroll
            for (int mi = 0; mi < MI; ++mi)
                af[mi] = *(const short8_t*)&As[buf][(wm + mi * 16 + l15) * 64 + fg];
            #pragma unroll
            for (int ni = 0; ni < 4; ++ni)
                bf[ni] = *(const short8_t*)&Bs[buf][(wn + ni * 16 + l15) * 64 + fg];
            #pragma unroll
            for (int mi = 0; mi < MI; ++mi)
                #pragma unroll
                for (int ni = 0; ni < 4; ++ni)
                    acc[mi][ni] = __builtin_amdgcn_mfma_f32_16x16x32_bf16(
                        af[mi], bf[ni], acc[mi][ni], 0, 0, 0);
        }
    }

    if (EPI == 4) {
        #pragma unroll
        for (int mi = 0; mi < MI; ++mi)
            #pragma unroll
            for (int r = 0; r < 4; ++r) {
                float s = 0.f;
                #pragma unroll
                for (int ni = 0; ni < 4; ++ni) {
                    const float x = acc[mi][ni][r];
                    s += x * x;
                }
                s += __shfl_xor(s, 1); s += __shfl_xor(s, 2);
                s += __shfl_xor(s, 4); s += __shfl_xor(s, 8);
                const float sc = 1.0f / fmaxf(sqrtf(s), 1e-6f);
                #pragma unroll
                for (int ni = 0; ni < 4; ++ni) acc[mi][ni][r] *= sc;
            }
    }

    const float a = (EPI == 1) ? alpha[0] : 0.f;
    #pragma unroll
    for (int mi = 0; mi < MI; ++mi) {
        #pragma unroll
        for (int ni = 0; ni < 4; ++ni) {
            const int n = bn + wn + ni * 16 + l15;
            const float bb = (EPI == 1) ? bias[n] : 0.f;
            #pragma unroll
            for (int r = 0; r < 4; ++r) {
                const int m = bm + wm + mi * 16 + (quad << 2) + r;
                const float x = acc[mi][ni][r];
                if (EPI == 4) {
                    out16[(size_t)m * N + n] = f2b(x);
                } else {
                    const size_t idx = (size_t)m * N + n;
                    outF[idx] = resF[idx] + a * (x + bb);
                }
            }
        }
    }
}

// ---------------------------------------------------------------------------
// Merged q-proj + kv-proj launch: 1-D grid 1536 with chunked XCD swizzle.
// bx<16: kv-proj (MX fp8, BM=128, BK=128, K=128 scaled MFMA — kept from
// r15, measured faster); bx>=16: q-proj (bf16). Pool 65536 B -> 2 blk/CU.
// ---------------------------------------------------------------------------
__device__ __forceinline__ void kvproj_body(
    unsigned char* __restrict__ pool, int bx, int by, int tid,
    const unsigned char* __restrict__ A, const unsigned char* __restrict__ W,
    short* __restrict__ khd, short* __restrict__ vhd)
{
    constexpr int BM = 128, BK = 128, MI = 4;
    constexpr int Kst = 1024;
    auto AsBuf = [&](int b) { return pool + b * (BM * BK); };
    auto BsBuf = [&](int b) { return pool + 2 * BM * BK + b * (128 * BK); };
    const int bm = by * BM, bn = bx * 128;
    const int wave = tid >> 6, lane = tid & 63;
    const int wm = (wave >> 1) * (BM / 2), wn = (wave & 1) * 64;
    const int l15 = lane & 15, quad = lane >> 4;
    const int l7 = l15 & 7;

    f32x4_t acc[MI][4];
    #pragma unroll
    for (int mi = 0; mi < MI; ++mi)
        #pragma unroll
        for (int ni = 0; ni < 4; ++ni)
            acc[mi][ni] = (f32x4_t){0.f, 0.f, 0.f, 0.f};

    auto stage = [&](int buf, int k0) {
        #pragma unroll
        for (int c = 0; c < 4; ++c) {                 // A: 128 rows x 128 B
            const int o = c * 4096 + tid * 16;
            const int row = o >> 7;
            const int g = ((o >> 4) & 7) ^ (row & 7);
            gload16(A + (size_t)(bm + row) * Kst + k0 + g * 16,
                    (char*)AsBuf(buf) + c * 4096 + wave * 1024);
        }
        #pragma unroll
        for (int c = 0; c < 4; ++c) {                 // B: 128 rows x 128 B
            const int o = c * 4096 + tid * 16;
            const int row = o >> 7;
            const int g = ((o >> 4) & 7) ^ (row & 7);
            gload16(W + (size_t)(bn + row) * Kst + k0 + g * 16,
                    (char*)BsBuf(buf) + c * 4096 + wave * 1024);
        }
    };

    const int ga = ((quad << 1) ^ l7) << 4;           // k bytes quad*32..+15
    const int gb = (((quad << 1) | 1) ^ l7) << 4;     // k bytes quad*32+16..+31

    stage(0, 0);
    for (int it = 0; it < 8; ++it) {
        const int buf = it & 1;
        __syncthreads();
        if (it + 1 < 8) stage(buf ^ 1, (it + 1) * BK);
        int8v_t af[MI], bf[4];
        #pragma unroll
        for (int mi = 0; mi < MI; ++mi)
            af[mi] = ld32(AsBuf(buf) + (wm + mi * 16 + l15) * BK, ga, gb);
        #pragma unroll
        for (int ni = 0; ni < 4; ++ni)
            bf[ni] = ld32(BsBuf(buf) + (wn + ni * 16 + l15) * BK, ga, gb);
        #pragma unroll
        for (int mi = 0; mi < MI; ++mi)
            #pragma unroll
            for (int ni = 0; ni < 4; ++ni)
                acc[mi][ni] = __builtin_amdgcn_mfma_scale_f32_16x16x128_f8f6f4(
                    af[mi], bf[ni], acc[mi][ni], 0, 0, 0, SCL1, 0, SCL1);
    }

    const bool isK = (bn < 1024);
    if (isK) {                               // l2norm (scale-invariant) for k
        #pragma unroll
        for (int mi = 0; mi < MI; ++mi)
            #pragma unroll
            for (int r = 0; r < 4; ++r) {
                float s = 0.f;
                #pragma unroll
                for (int ni = 0; ni < 4; ++ni) {
                    const float x = acc[mi][ni][r];
                    s += x * x;
                }
                s += __shfl_xor(s, 1); s += __shfl_xor(s, 2);
                s += __shfl_xor(s, 4); s += __shfl_xor(s, 8);
                const float sc = 1.0f / fmaxf(sqrtf(s), 1e-6f);
                #pragma unroll
                for (int ni = 0; ni < 4; ++ni) acc[mi][ni][r] *= sc;
            }
    }
    __syncthreads();                         // all waves done with As/Bs
    short* Ct = (short*)pool;                // [128][136] bf16
    constexpr int LDC = 136;
    if (isK) {                               // Ct[m][n]
        #pragma unroll
        for (int mi = 0; mi < MI; ++mi)
            #pragma unroll
            for (int ni = 0; ni < 4; ++ni) {
                const int n = wn + ni * 16 + l15;
                #pragma unroll
                for (int r = 0; r < 4; ++r)
                    Ct[(wm + mi * 16 + (quad << 2) + r) * LDC + n] =
                        f2b(acc[mi][ni][r]);
            }
    } else {                                 // Ct[n][m], pack 4 m as short4
        #pragma unroll
        for (int mi = 0; mi < MI; ++mi)
            #pragma unroll
            for (int ni = 0; ni < 4; ++ni) {
                short4 pk;
                pk.x = f2b(acc[mi][ni][0] * OSC);
                pk.y = f2b(acc[mi][ni][1] * OSC);
                pk.z = f2b(acc[mi][ni][2] * OSC);
                pk.w = f2b(acc[mi][ni][3] * OSC);
                *(short4*)&Ct[(wn + ni * 16 + l15) * LDC +
                              wm + mi * 16 + (quad << 2)] = pk;
            }
    }
    __syncthreads();
    const int b_ = bm >> 11;
    const int kv0 = bm & 2047;
    #pragma unroll
    for (int p = 0; p < 8; ++p) {
        const int idx = p * 256 + tid;
        const int row = idx >> 4, ch = idx & 15;   // 128 rows x 16 chunks
        const short8_t v = *(const short8_t*)&Ct[row * LDC + ch * 8];
        if (isK) {            // row=m (kv), chunk covers n: 2 heads x 64 d
            const int hh = (bn >> 6) + (ch >> 3);
            *(short8_t*)&khd[(size_t)((b_ * 16 + hh) * 2048 + kv0 + row) * 64 +
                             (ch & 7) * 8] = v;
        } else {              // row=n (head,d), chunk covers m (kv)
            const int nn = bn - 1024 + row;
            *(short8_t*)&vhd[(size_t)((b_ * 16 + (nn >> 6)) * 64 +
                             (nn & 63)) * 2048 + kv0 + ch * 8] = v;
        }
    }
}

__device__ __forceinline__ void qproj_body(
    unsigned char* __restrict__ pool, int bx, int by, int tid,
    const short* __restrict__ A, const short* __restrict__ W,
    short* __restrict__ out16)
{
    constexpr int BM = 32, N = 1024, Kst = 1024;
    short* As = (short*)pool;                     // 2 bufs x BM*64 (8192 B)
    short* Bs = (short*)(pool + 8192);            // 2 bufs x 128*64 (32768 B)
    const int bm = by * BM, bn = bx * 128;
    const int wave = tid >> 6, lane = tid & 63;
    const int wm = (wave >> 1) * 16, wn = (wave & 1) * 64;
    const int l15 = lane & 15, quad = lane >> 4;
    const int l7 = l15 & 7;

    f32x4_t acc[4];
    #pragma unroll
    for (int ni = 0; ni < 4; ++ni) acc[ni] = (f32x4_t){0.f, 0.f, 0.f, 0.f};

    auto stage = [&](int buf, int k0) {
        {
            const int o = tid * 16;               // A: 32 rows x 128 B
            const int row = o >> 7;
            const int g = ((o >> 4) & 7) ^ (row & 7);
            gload16(A + (size_t)(bm + row) * Kst + k0 + g * 8,
                    (char*)As + buf * 4096 + wave * 1024);
        }
        #pragma unroll
        for (int c = 0; c < 4; ++c) {             // B: 128 rows x 128 B
            const int o = c * 4096 + tid * 16;
            const int row = o >> 7;
            const int g = ((o >> 4) & 7) ^ (row & 7);
            gload16(W + (size_t)(bn + row) * Kst + k0 + g * 8,
                    (char*)Bs + buf * 16384 + c * 4096 + wave * 1024);
        }
    };

    stage(0, 0);
    for (int it = 0; it < 16; ++it) {
        const int buf = it & 1;
        __syncthreads();
        if (it + 1 < 16) stage(buf ^ 1, (it + 1) * 64);
        #pragma unroll
        for (int h = 0; h < 2; ++h) {
            const int fg = (((h << 2) | quad) ^ l7) * 8;
            const short8_t af =
                *(const short8_t*)&As[buf * 2048 + (wm + l15) * 64 + fg];
            short8_t bf[4];
            #pragma unroll
            for (int ni = 0; ni < 4; ++ni)
                bf[ni] = *(const short8_t*)&Bs[buf * 8192 +
                                               (wn + ni * 16 + l15) * 64 + fg];
            #pragma unroll
            for (int ni = 0; ni < 4; ++ni)
                acc[ni] = __builtin_amdgcn_mfma_f32_16x16x32_bf16(
                    af, bf[ni], acc[ni], 0, 0, 0);
        }
    }

    // l2norm over each 64-col head slice (wn selects head half)
    #pragma unroll
    for (int r = 0; r < 4; ++r) {
        float s = 0.f;
        #pragma unroll
        for (int ni = 0; ni < 4; ++ni) {
            const float x = acc[ni][r];
            s += x * x;
        }
        s += __shfl_xor(s, 1); s += __shfl_xor(s, 2);
        s += __shfl_xor(s, 4); s += __shfl_xor(s, 8);
        const float sc = 1.0f / fmaxf(sqrtf(s), 1e-6f);
        #pragma unroll
        for (int ni = 0; ni < 4; ++ni) acc[ni][r] *= sc;
    }
    #pragma unroll
    for (int ni = 0; ni < 4; ++ni) {
        const int n = bn + wn + ni * 16 + l15;
        #pragma unroll
        for (int r = 0; r < 4; ++r) {
            const int m = bm + wm + (quad << 2) + r;
            out16[(size_t)m * N + n] = f2b(acc[ni][r]);
        }
    }
}

__global__ __launch_bounds__(256, 2) void qkv_kernel(
    const unsigned char* __restrict__ kvn8, const unsigned char* __restrict__ Wkv8,
    short* __restrict__ khd, short* __restrict__ vhd,
    const short* __restrict__ qn, const short* __restrict__ Wq_b,
    short* __restrict__ qbuf)
{
    __shared__ __attribute__((aligned(16))) unsigned char pool[65536];
    const int id = blockIdx.x;               // 0..1535
    const int xcd = id & 7, slot = id >> 3;  // chunked XCD swizzle (r14)
    const int by = xcd * 8 + (slot & 7);     // 0..63: band per XCD
    const int bx = slot >> 3;                // 0..23
    const int tid = threadIdx.x;
    if (bx < 16) kvproj_body(pool, bx, by, tid, kvn8, Wkv8, khd, vhd);
    else         qproj_body(pool, bx - 16, by, tid, qn, Wq_b, qbuf);
}

// ---------------------------------------------------------------------------
// fp8 GEMM (fc1, fc2): non-scaled K=32, BN=128, BK=64, dbuf single-barrier
// (r14 version — MX K=128 port of these regressed; reverted).
// EPI: 2 fc1: fp8 out8 = gelu(acc*OSC + bias)   [LDS-staged coalesced 16B]
//      7 fc2 split-K partial: out16 + z*M*N = bf16(acc)  (raw x16 scale)
// ---------------------------------------------------------------------------
template <int EPI, int BM, int BK>
__global__ __launch_bounds__(256, 4) void gemm_f8_kernel(
    const unsigned char* __restrict__ A, const unsigned char* __restrict__ W,
    int M, int N, int Ks, int Kst,
    const float* __restrict__ bias,
    unsigned char* __restrict__ out8,
    short* __restrict__ out16,
    float* __restrict__ outF)
{
    constexpr int MI = BM / 32;
    constexpr int KS = BK / 32;
    constexpr int STG = 2 * BM * BK + 2 * 128 * BK;
    constexpr int EPIB = (EPI == 2) ? BM * 144 : 0;
    constexpr int POOL = (STG > EPIB) ? STG : EPIB;
    __shared__ __attribute__((aligned(16))) unsigned char pool[POOL];
    auto AsBuf = [&](int b) { return pool + b * (BM * BK); };
    auto BsBuf = [&](int b) { return pool + 2 * BM * BK + b * (128 * BK); };
    const int bm = blockIdx.y * BM, bn = blockIdx.x * 128;
    const size_t kbase = (size_t)blockIdx.z * Ks;
    const int tid = threadIdx.x;
    const int wave = tid >> 6, lane = tid & 63;
    const int wm = (wave >> 1) * (BM / 2), wn = (wave & 1) * 64;
    const int l15 = lane & 15, quad = lane >> 4;
    const int l7 = l15 & 7;

    f32x4_t acc[MI][4];
    #pragma unroll
    for (int mi = 0; mi < MI; ++mi)
        #pragma unroll
        for (int ni = 0; ni < 4; ++ni)
            acc[mi][ni] = (f32x4_t){0.f, 0.f, 0.f, 0.f};

    auto stage = [&](int buf, int k0) {
        #pragma unroll
        for (int c = 0; c < BM * BK / 4096; ++c) {
            const int o = c * 4096 + tid * 16;
            const int row = o / BK;
            int g;
            if constexpr (BK == 128) g = ((o >> 4) & 7) ^ (row & 7);
            else                     g = ((o >> 4) & 3) ^ ((row >> 1) & 3);
            gload16(A + (size_t)(bm + row) * Kst + kbase + k0 + g * 16,
                    (char*)AsBuf(buf) + c * 4096 + wave * 1024);
        }
        #pragma unroll
        for (int c = 0; c < 128 * BK / 4096; ++c) {
            const int o = c * 4096 + tid * 16;
            const int row = o / BK;
            int g;
            if constexpr (BK == 128) g = ((o >> 4) & 7) ^ (row & 7);
            else                     g = ((o >> 4) & 3) ^ ((row >> 1) & 3);
            gload16(W + (size_t)(bn + row) * Kst + kbase + k0 + g * 16,
                    (char*)BsBuf(buf) + c * 4096 + wave * 1024);
        }
    };

    const int nIter = Ks / BK;
    stage(0, 0);
    for (int it = 0; it < nIter; ++it) {
        const int buf = it & 1;
        __syncthreads();
        if (it + 1 < nIter) stage(buf ^ 1, (it + 1) * BK);
        #pragma unroll
        for (int ks = 0; ks < KS; ++ks) {
            int fo;
            if constexpr (BK == 128)
                fo = ((((ks << 1) | (quad >> 1)) ^ l7) << 4) + (quad & 1) * 8;
            else
                fo = ((((ks << 1) | (quad >> 1)) ^ ((l15 >> 1) & 3)) << 4) +
                     (quad & 1) * 8;
            long af[MI], bf[4];
            #pragma unroll
            for (int mi = 0; mi < MI; ++mi)
                af[mi] = *(const long*)(AsBuf(buf) + (wm + mi * 16 + l15) * BK + fo);
            #pragma unroll
            for (int ni = 0; ni < 4; ++ni)
                bf[ni] = *(const long*)(BsBuf(buf) + (wn + ni * 16 + l15) * BK + fo);
            #pragma unroll
            for (int mi = 0; mi < MI; ++mi)
                #pragma unroll
                for (int ni = 0; ni < 4; ++ni)
                    acc[mi][ni] = __builtin_amdgcn_mfma_f32_16x16x32_fp8_fp8(
                        af[mi], bf[ni], acc[mi][ni], 0, 0, 0);
        }
    }

    if (EPI == 2) {                            // fc1 + GELU, LDS-staged fp8
        __syncthreads();
        unsigned char* C8 = (unsigned char*)pool;   // [BM][144] fp8
        constexpr int LDC8 = 144;
        #pragma unroll
        for (int mi = 0; mi < MI; ++mi)
            #pragma unroll
            for (int ni = 0; ni < 4; ++ni) {
                const int n = wn + ni * 16 + l15;
                const float bb = bias[bn + n];
                #pragma unroll
                for (int r = 0; r < 4; ++r) {
                    const float t = acc[mi][ni][r] * OSC + bb;
                    C8[(wm + mi * 16 + (quad << 2) + r) * LDC8 + n] =
                        f2f8(0.5f * t * (1.0f + erff(t * 0.70710678118f)));
                }
            }
        __syncthreads();
        #pragma unroll
        for (int p = 0; p < MI; ++p) {
            const int idx = p * 256 + tid;
            const int row = idx >> 3, ch = idx & 7;
            const f32x4_t v = *(const f32x4_t*)&C8[row * LDC8 + ch * 16];
            *(f32x4_t*)&out8[(size_t)(bm + row) * N + bn + ch * 16] = v;
        }
        return;
    }

    // EPI == 7: fc2 split-K bf16 partials (raw x16 scale; reduce applies OSC)
    #pragma unroll
    for (int mi = 0; mi < MI; ++mi) {
        #pragma unroll
        for (int ni = 0; ni < 4; ++ni) {
            const int n = bn + wn + ni * 16 + l15;
            #pragma unroll
            for (int r = 0; r < 4; ++r) {
                const int m = bm + wm + mi * 16 + (quad << 2) + r;
                out16[(size_t)blockIdx.z * M * N + (size_t)m * N + n] =
                    f2b(acc[mi][ni][r]);
            }
        }
    }
}

// ---------------------------------------------------------------------------
// Split-K reduce for fc2 (bf16 partials):
// out = resF + alpha*((p0+p1+p2+p3)*OSC + bias).
// ---------------------------------------------------------------------------
__global__ __launch_bounds__(256) void reduce4_kernel(
    const short* __restrict__ parts, const float* __restrict__ resF,
    const float* __restrict__ bias, const float* __restrict__ alpha,
    float* __restrict__ out)
{
    const int i = blockIdx.x * 256 + threadIdx.x;   // short4 idx over 2048x1024
    const size_t MN4 = (size_t)2048 * 1024 / 4;
    const float a = alpha[0];
    const float4 b4 = ((const float4*)bias)[i & 255];
    const short4 p0 = ((const short4*)parts)[i];
    const short4 p1 = ((const short4*)parts)[MN4 + i];
    const short4 p2 = ((const short4*)parts)[2 * MN4 + i];
    const short4 p3 = ((const short4*)parts)[3 * MN4 + i];
    const float4 rv = ((const float4*)resF)[i];
    float4 o;
    o.x = rv.x + a * ((b2f(p0.x) + b2f(p1.x) + b2f(p2.x) + b2f(p3.x)) * OSC + b4.x);
    o.y = rv.y + a * ((b2f(p0.y) + b2f(p1.y) + b2f(p2.y) + b2f(p3.y)) * OSC + b4.y);
    o.z = rv.z + a * ((b2f(p0.z) + b2f(p1.z) + b2f(p2.z) + b2f(p3.z)) * OSC + b4.z);
    o.w = rv.w + a * ((b2f(p0.w) + b2f(p1.w) + b2f(p2.w) + b2f(p3.w)) * OSC + b4.w);
    ((float4*)out)[i] = o;
}

// ---------------------------------------------------------------------------
// Attention (r10 + r13 bf16 partials + r14 setprio): KV-split x2, K/V
// LDS-staged, zero cross-lane softmax. Grid (h=16, b=4, qt*2+sp=16) = 1024
// blocks; LDS 32768 B -> 4 blocks/CU. Same-head blocks land on one XCD.
// Swapped QK -> P is the 16x16x16 MFMA A-fragment; PV + row-sum via mfma16.
// ---------------------------------------------------------------------------
__global__ __launch_bounds__(256, 4) void attn_kernel(
    const short* __restrict__ q, const short* __restrict__ khd,
    const short* __restrict__ vhd, short* __restrict__ o0,
    short* __restrict__ o1, float* __restrict__ lpart)
{
    const int h  = blockIdx.x;        // 0..15
    const int b  = blockIdx.y;        // 0..3
    const int qt = blockIdx.z >> 1;   // 0..7
    const int sp = blockIdx.z & 1;    // kv-split 0..1
    const int tid = threadIdx.x;
    const int wave = tid >> 6, lane = tid & 63;
    const int l15 = lane & 15, quad = lane >> 4;
    const int q0 = qt * 64 + wave * 16;
    const int t0 = sp * 16;           // first KV tile for this split

    __shared__ __attribute__((aligned(16))) short Ks[2][4096];
    __shared__ __attribute__((aligned(16))) short Vs[2][4096];

    const short* qbase = q + (size_t)(b * 512 + q0 + l15) * 1024 + h * 64 + quad * 8;
    const short8_t aq0 = *(const short8_t*)(qbase);
    const short8_t aq1 = *(const short8_t*)(qbase + 32);

    const short* kbase = khd + (size_t)(b * 16 + h) * 2048 * 64;  // [2048][64]
    const short* vbase = vhd + (size_t)(b * 16 + h) * 64 * 2048;  // [64][2048]

    const int swz = l15 & 7;
    const int g0 = (quad ^ swz) * 8;
    const int g1 = ((quad ^ swz) ^ 4) * 8;

    auto stage = [&](int buf, int t) {
        #pragma unroll
        for (int c = 0; c < 2; ++c) {
            const int o = c * 4096 + tid * 16;
            const int row = o >> 7;              // 64 rows x 128 B
            const int g = ((o >> 4) & 7) ^ (row & 7);
            gload16(kbase + (size_t)(t * 64 + row) * 64 + g * 8,
                    (char*)Ks[buf] + c * 4096 + wave * 1024);
            gload16(vbase + (size_t)row * 2048 + t * 64 + g * 8,
                    (char*)Vs[buf] + c * 4096 + wave * 1024);
        }
    };

    const short4_t ones4 = {(short)0x3F80, (short)0x3F80,
                            (short)0x3F80, (short)0x3F80};   // 4 x bf16 1.0

    f32x4_t oacc[4];
    #pragma unroll
    for (int u = 0; u < 4; ++u) oacc[u] = (f32x4_t){0.f, 0.f, 0.f, 0.f};
    f32x4_t lacc = (f32x4_t){0.f, 0.f, 0.f, 0.f};

    stage(0, t0);
    for (int tt = 0; tt < 16; ++tt) {
        const int buf = tt & 1;
        __syncthreads();
        if (tt + 1 < 16) stage(buf ^ 1, t0 + tt + 1);

        // swapped QK^T: s[ss] holds P-pre[kv=ss*16+quad*4+r][q=l15]
        f32x4_t s[4];
        __builtin_amdgcn_s_setprio(1);
        #pragma unroll
        for (int ss = 0; ss < 4; ++ss) {
            const int R = ss * 16 + l15;
            const short8_t bk0 = *(const short8_t*)&Ks[buf][R * 64 + g0];
            const short8_t bk1 = *(const short8_t*)&Ks[buf][R * 64 + g1];
            f32x4_t a = (f32x4_t){0.f, 0.f, 0.f, 0.f};
            a = __builtin_amdgcn_mfma_f32_16x16x32_bf16(bk0, aq0, a, 0, 0, 0);
            a = __builtin_amdgcn_mfma_f32_16x16x32_bf16(bk1, aq1, a, 0, 0, 0);
            s[ss] = a;
        }
        __builtin_amdgcn_s_setprio(0);
        // exp + pack: pa[ss] = A-fragment P^T[q=l15][kv local quad*4+j]
        short4_t pa[4];
        #pragma unroll
        for (int ss = 0; ss < 4; ++ss) {
            const float p0 = __expf(s[ss][0] * 0.5f);
            const float p1 = __expf(s[ss][1] * 0.5f);
            const float p2 = __expf(s[ss][2] * 0.5f);
            const float p3 = __expf(s[ss][3] * 0.5f);
            union { unsigned w[2]; short4_t v; } u_;
            u_.w[0] = cvt_pk_bf16(p0, p1);
            u_.w[1] = cvt_pk_bf16(p2, p3);
            pa[ss] = u_.v;
        }
        __builtin_amdgcn_s_setprio(1);
        // row-sum: l[q] += sum_kv P
        #pragma unroll
        for (int ss = 0; ss < 4; ++ss)
            lacc = __builtin_amdgcn_mfma_f32_16x16x16bf16_1k(
                pa[ss], ones4, lacc, 0, 0, 0);
        // PV: oacc[u] += P^T x V, K=16 per ss; V frag = ds_read_b64
        #pragma unroll
        for (int ss = 0; ss < 4; ++ss) {
            const int ch = (((ss * 2 + (quad >> 1)) ^ swz) << 3) + ((quad & 1) << 2);
            #pragma unroll
            for (int u = 0; u < 4; ++u) {
                const short4_t bv =
                    *(const short4_t*)&Vs[buf][(u * 16 + l15) * 64 + ch];
                oacc[u] = __builtin_amdgcn_mfma_f32_16x16x16bf16_1k(
                    pa[ss], bv, oacc[u], 0, 0, 0);
            }
        }
        __builtin_amdgcn_s_setprio(0);
    }

    // raw bf16 partial writes (no normalization here)
    short* ob = sp ? o1 : o0;
    float* lb = lpart + (size_t)sp * 2048 * 16;
    #pragma unroll
    for (int u = 0; u < 4; ++u)
        #pragma unroll
        for (int r = 0; r < 4; ++r)
            ob[(size_t)(b * 512 + q0 + quad * 4 + r) * 1024 + h * 64 + u * 16 + l15] =
                f2b(oacc[u][r]);
    if (l15 == 0) {
        #pragma unroll
        for (int r = 0; r < 4; ++r)
            lb[(size_t)(b * 512 + q0 + quad * 4 + r) * 16 + h] = lacc[r];
    }
}

// ---------------------------------------------------------------------------
// Combine the two KV-split bf16 partials: ctx = (o0+o1)/(l0+l1) -> bf16.
// ---------------------------------------------------------------------------
__global__ __launch_bounds__(256) void attn_combine_kernel(
    const short* __restrict__ o0, const short* __restrict__ o1,
    const float* __restrict__ lpart, short* __restrict__ ctx)
{
    const int i = blockIdx.x * 256 + threadIdx.x;   // short4 idx over 2048x1024
    const int row = i >> 8;
    const int h = (i & 255) >> 4;
    const float l = lpart[row * 16 + h] + lpart[2048 * 16 + row * 16 + h];
    const float inv = 1.0f / l;
    const short4 a4 = ((const short4*)o0)[i];
    const short4 c4 = ((const short4*)o1)[i];
    short4 o;
    o.x = f2b((b2f(a4.x) + b2f(c4.x)) * inv);
    o.y = f2b((b2f(a4.y) + b2f(c4.y)) * inv);
    o.z = f2b((b2f(a4.z) + b2f(c4.z)) * inv);
    o.w = f2b((b2f(a4.w) + b2f(c4.w)) * inv);
    ((short4*)ctx)[i] = o;
}

// ---------------------------------------------------------------------------
extern "C" void kernel_launch(void* const* d_in, const int* in_sizes, int n_in,
                              void* d_out, int out_size, void* d_ws, size_t ws_size,
                              hipStream_t stream)
{
    const float* q_tokens  = (const float*)d_in[0];
    const float* kv_tokens = (const float*)d_in[1];
    const float* q_ln_w    = (const float*)d_in[2];
    const float* q_ln_b    = (const float*)d_in[3];
    const float* kv_ln_w   = (const float*)d_in[4];
    const float* kv_ln_b   = (const float*)d_in[5];
    const float* mlp_ln_w  = (const float*)d_in[6];
    const float* mlp_ln_b  = (const float*)d_in[7];
    const float* Wq        = (const float*)d_in[8];
    const float* Wk        = (const float*)d_in[9];
    const float* Wv        = (const float*)d_in[10];
    const float* Wo        = (const float*)d_in[11];
    const float* bo        = (const float*)d_in[12];
    const float* fc1_w     = (const float*)d_in[13];
    const float* fc1_b     = (const float*)d_in[14];
    const float* fc2_w     = (const float*)d_in[15];
    const float* fc2_b     = (const float*)d_in[16];
    const float* alpha_attn = (const float*)d_in[17];
    const float* alpha_mlp  = (const float*)d_in[18];

    char* ws = (char*)d_ws;
    const size_t MB = (size_t)1 << 20;
    short* khd    = (short*)(ws);             // 16 MB [4,16,2048,64]; dead after attn
    short* vhd    = (short*)(ws + 16 * MB);   // 16 MB [4,16,64,2048]; dead after attn
    short* parts  = (short*)(ws);             // 16 MB fc2 bf16 partials (overlays khd)
    unsigned char* kvn8 = (unsigned char*)(ws + 32 * MB); // 8 MB; dead after kv-gemm
    short* attn_o0 = (short*)(ws + 32 * MB);  //    overlays kvn8: 4 MB bf16 partial
    unsigned char* h1   = (unsigned char*)(ws + 32 * MB); //  overlays kvn8: 8 MB fp8
    short* qn     = (short*)(ws + 40 * MB);   //  4 MB [2048,1024] bf16
    short* qbuf   = (short*)(ws + 44 * MB);   //  4 MB [2048,1024] bf16 (l2-normed q)
    short* ctx    = (short*)(ws + 48 * MB);   //  4 MB [2048,1024] bf16
    float* aout   = (float*)(ws + 52 * MB);   //  8 MB [2048,1024] fp32
    short* attn_o1 = (short*)(ws + 52 * MB);  //    overlays aout: 4 MB bf16 partial
    unsigned char* hn8 = (unsigned char*)(ws + 60 * MB);  // 2 MB fp8
    float* attn_l  = (float*)(ws + 60 * MB);  //    overlays hn8: 256 KB [2,2048,16]
    short* Wq_b   = (short*)(ws + 62 * MB);   //  2 MB bf16
    short* Wo_b   = (short*)(ws + 64 * MB);   //  2 MB bf16
    unsigned char* Wkv8  = (unsigned char*)(ws + 66 * MB); // 2 MB fp8 stacked
    unsigned char* fc1_8 = (unsigned char*)(ws + 68 * MB); // 4 MB fp8
    unsigned char* fc2_8 = (unsigned char*)(ws + 72 * MB); // 4 MB fp8

    // 0) fused: q-LN(bf16) + kv-LN(fp8) + weight casts
    prep_kernel<<<22528, 256, 0, stream>>>(
        q_tokens, kv_tokens, q_ln_w, q_ln_b, kv_ln_w, kv_ln_b, qn, kvn8,
        Wq, Wo, Wk, Wv, fc1_w, fc2_w,
        Wq_b, Wo_b, Wkv8, fc1_8, fc2_8);

    // 1) merged q-proj (+l2norm) and kv-proj (MX fp8, fused l2norm/scatter)
    qkv_kernel<<<1536, 256, 0, stream>>>(
        kvn8, Wkv8, khd, vhd, qn, Wq_b, qbuf);

    // 2) Attention: KV-split x2, bf16 partials; combine normalizes -> ctx
    attn_kernel<<<dim3(16, 4, 16), 256, 0, stream>>>(
        qbuf, khd, vhd, attn_o0, attn_o1, attn_l);
    attn_combine_kernel<<<2048, 256, 0, stream>>>(attn_o0, attn_o1, attn_l, ctx);

    // 3) Out-proj + residual (bf16, BM=32)
    gemm_bt_kernel<1, 32><<<dim3(8, 64), 256, 0, stream>>>(
        ctx, Wo_b, 2048, 1024, 1024, 1024, bo, q_tokens, alpha_attn, nullptr, aout);

    // 4) MLP LN -> fp8
    ln8_kernel<<<2048, 256, 0, stream>>>(aout, mlp_ln_w, mlp_ln_b, hn8);

    // 5) fc1 (fp8, BM=64,BK=64, 4 blk/CU) + exact GELU -> fp8 h1
    gemm_f8_kernel<2, 64, 64><<<dim3(32, 32), 256, 0, stream>>>(
        hn8, fc1_8, 2048, 4096, 1024, 1024, fc1_b, h1, nullptr, nullptr);

    // 6) fc2 (fp8, BK=64) split-K x4 -> bf16 partials, reduce -> d_out
    gemm_f8_kernel<7, 64, 64><<<dim3(8, 32, 4), 256, 0, stream>>>(
        h1, fc2_8, 2048, 1024, 1024, 4096, nullptr, nullptr, parts, nullptr);
    reduce4_kernel<<<2048, 256, 0, stream>>>(parts, aout, fc2_b, alpha_mlp,
                                             (float*)d_out);
}